// Round 1
// baseline (935.023 us; speedup 1.0000x reference)
//
#include <hip/hip_runtime.h>
#include <cstddef>

#define B_SZ 64
#define HID_ 4096
#define NH_ 32
#define NKV_ 8
#define HD_ 128
#define T_ 4096
#define QKV_COLS 6144           // (NH + 2*NKV) * HD
#define SCALE_ 0.08838834764831845f  // 128^-0.5

#define KS 16                   // split-K factor for both GEMMs
#define IPER 256                // HID_/KS

#define SPLIT_ 4
#define KPB 1024                // keys per block (T_/SPLIT_)
#define NTILE 16                // KPB/64

// ---------------- split-K GEMM partial: part[ks][64][ncol] += X[64][4096] @ W[4096][ncol]
__global__ __launch_bounds__(256) void gemm_part_k(const float* __restrict__ X,
                                                   const float* __restrict__ W,
                                                   float* __restrict__ part, int ncol) {
  __shared__ float xs[IPER][68];   // transposed X tile: xs[ii][b]; pad 68 keeps b128 reads aligned
  const int tid = threadIdx.x;
  const int i0 = blockIdx.y * IPER;
  for (int r = 0; r < 64; ++r) {
    xs[tid][r] = X[(size_t)r * HID_ + i0 + tid];
  }
  __syncthreads();
  const int o = blockIdx.x * 256 + tid;
  float acc[64];
#pragma unroll
  for (int b = 0; b < 64; ++b) acc[b] = 0.f;
  const float* wp = W + (size_t)i0 * ncol + o;
  for (int ii = 0; ii < IPER; ++ii) {
    float wv = wp[(size_t)ii * ncol];
#pragma unroll
    for (int j = 0; j < 16; ++j) {
      float4 hv = *(const float4*)&xs[ii][4 * j];
      acc[4 * j + 0] += hv.x * wv;
      acc[4 * j + 1] += hv.y * wv;
      acc[4 * j + 2] += hv.z * wv;
      acc[4 * j + 3] += hv.w * wv;
    }
  }
  float* pp = part + (size_t)blockIdx.y * 64 * ncol + o;
  for (int b = 0; b < 64; ++b) pp[(size_t)b * ncol] = acc[b];
}

__global__ __launch_bounds__(256) void reduce16_k(const float* __restrict__ part,
                                                  float* __restrict__ out, int n) {
  int idx = blockIdx.x * 256 + threadIdx.x;
  if (idx >= n) return;
  float s = 0.f;
#pragma unroll
  for (int k = 0; k < KS; ++k) s += part[(size_t)k * n + idx];
  out[idx] = s;
}

// ---------------- RoPE on new q/k, plus v copy-out
__global__ __launch_bounds__(64) void rope_k(const float* __restrict__ qkv,
                                             const int* __restrict__ pos,
                                             float* __restrict__ qr,
                                             float* __restrict__ kn,
                                             float* __restrict__ vn) {
  const int b = blockIdx.x;
  const int hh = blockIdx.y;      // 0..31 = q heads, 32..39 = k heads
  const int d = threadIdx.x;      // 0..63
  const float p = (float)pos[b];
  const float invf = (float)pow(10000.0, -(double)d / 64.0);
  float sn, cs;
  sincosf(p * invf, &sn, &cs);
  const float* src;
  float* dst;
  if (hh < 32) {
    src = qkv + (size_t)b * QKV_COLS + hh * HD_;
    dst = qr + ((size_t)b * NH_ + hh) * HD_;
  } else {
    const int g = hh - 32;
    src = qkv + (size_t)b * QKV_COLS + NH_ * HD_ + g * HD_;
    dst = kn + ((size_t)b * NKV_ + g) * HD_;
    const float* vsrc = qkv + (size_t)b * QKV_COLS + (NH_ + NKV_) * HD_ + g * HD_;
    float* vdst = vn + ((size_t)b * NKV_ + g) * HD_;
    vdst[d] = vsrc[d];
    vdst[d + 64] = vsrc[d + 64];
  }
  const float x1 = src[d], x2 = src[d + 64];
  dst[d] = x1 * cs - x2 * sn;
  dst[d + 64] = x2 * cs + x1 * sn;
}

// ---------------- flash-decode attention: one block per (b, kv-head, split)
__global__ __launch_bounds__(256) void attn_k(const float* __restrict__ kc,
                                              const float* __restrict__ vc,
                                              const float* __restrict__ qr,
                                              const float* __restrict__ kn,
                                              const float* __restrict__ vn,
                                              float* __restrict__ part) {
  __shared__ float kv_s[64][129];   // K or V tile; pad 129 -> 2-way alias (free) on score reads
  __shared__ float s_all[4][KPB];   // scores then probs, per head
  __shared__ float q_s[4][HD_];
  const int b = blockIdx.x, g = blockIdx.y, sp = blockIdx.z;
  const int tid = threadIdx.x;
  const int w = tid >> 6;           // wave == head within GQA group
  const int l = tid & 63;
  for (int e = tid; e < 4 * HD_; e += 256) {
    int hh = e >> 7, d = e & 127;
    q_s[hh][d] = qr[((size_t)b * NH_ + g * 4 + hh) * HD_ + d] * SCALE_;
  }
  __syncthreads();
  const float* kbase = kc + ((size_t)b * T_ * NKV_ + g) * HD_;
  const float* vbase = vc + ((size_t)b * T_ * NKV_ + g) * HD_;
  const int t0b = sp * KPB;

  // ---- phase 1: scores for 1024 keys
  for (int tile = 0; tile < NTILE; ++tile) {
    const float* kt = kbase + (size_t)(t0b + tile * 64) * (NKV_ * HD_);
#pragma unroll
    for (int it = 0; it < 8; ++it) {
      int e = it * 256 + tid;
      int key = e >> 5, j = (e & 31) * 4;
      float4 v4 = *(const float4*)(kt + (size_t)key * (NKV_ * HD_) + j);
      kv_s[key][j + 0] = v4.x;
      kv_s[key][j + 1] = v4.y;
      kv_s[key][j + 2] = v4.z;
      kv_s[key][j + 3] = v4.w;
    }
    __syncthreads();
    float s = 0.f;
#pragma unroll
    for (int d = 0; d < HD_; ++d) s += q_s[w][d] * kv_s[l][d];
    s_all[w][tile * 64 + l] = s;
    __syncthreads();
  }

  // ---- new-token score (only the last split owns key T)
  const bool has_new = (sp == SPLIT_ - 1);
  float s_new = 0.f;
  if (has_new) {
    const float* knp = kn + ((size_t)b * NKV_ + g) * HD_;
    float pq = q_s[w][l] * knp[l] + q_s[w][l + 64] * knp[l + 64];
#pragma unroll
    for (int m = 32; m > 0; m >>= 1) pq += __shfl_xor(pq, m);
    s_new = pq;
  }

  // ---- per-head (per-wave) partial softmax over this split
  float vals[16];
  float mloc = -1e30f;
#pragma unroll
  for (int k = 0; k < 16; ++k) {
    vals[k] = s_all[w][k * 64 + l];
    mloc = fmaxf(mloc, vals[k]);
  }
#pragma unroll
  for (int m = 32; m > 0; m >>= 1) mloc = fmaxf(mloc, __shfl_xor(mloc, m));
  if (has_new) mloc = fmaxf(mloc, s_new);
  float lsum = 0.f;
#pragma unroll
  for (int k = 0; k < 16; ++k) {
    float e = expf(vals[k] - mloc);
    lsum += e;
    s_all[w][k * 64 + l] = e;
  }
#pragma unroll
  for (int m = 32; m > 0; m >>= 1) lsum += __shfl_xor(lsum, m);
  float e_new = 0.f;
  if (has_new) {
    e_new = expf(s_new - mloc);
    lsum += e_new;
  }

  // ---- phase 2: PV accumulate; thread owns (head w, dims 2l, 2l+1)
  float acc0 = 0.f, acc1 = 0.f;
  const int d0 = 2 * l;
  for (int tile = 0; tile < NTILE; ++tile) {
    const float* vt = vbase + (size_t)(t0b + tile * 64) * (NKV_ * HD_);
#pragma unroll
    for (int it = 0; it < 8; ++it) {
      int e = it * 256 + tid;
      int key = e >> 5, j = (e & 31) * 4;
      float4 v4 = *(const float4*)(vt + (size_t)key * (NKV_ * HD_) + j);
      kv_s[key][j + 0] = v4.x;
      kv_s[key][j + 1] = v4.y;
      kv_s[key][j + 2] = v4.z;
      kv_s[key][j + 3] = v4.w;
    }
    __syncthreads();
#pragma unroll
    for (int t = 0; t < 64; ++t) {
      float pbc = s_all[w][tile * 64 + t];
      acc0 += pbc * kv_s[t][d0];
      acc1 += pbc * kv_s[t][d0 + 1];
    }
    __syncthreads();
  }
  if (has_new) {
    const float* vnp = vn + ((size_t)b * NKV_ + g) * HD_;
    acc0 += e_new * vnp[d0];
    acc1 += e_new * vnp[d0 + 1];
  }

  float* pp = part + ((size_t)(b * NH_ + g * 4 + w) * SPLIT_ + sp) * 130;
  pp[d0] = acc0;
  pp[d0 + 1] = acc1;
  if (l == 0) {
    pp[128] = mloc;
    pp[129] = lsum;
  }
}

// ---------------- merge the 4 split partials per (b, head)
__global__ __launch_bounds__(64) void merge_k(const float* __restrict__ part,
                                              float* __restrict__ ctx) {
  const int bh = blockIdx.x;        // b*32 + h
  const int l = threadIdx.x;
  const float* pbase = part + (size_t)bh * SPLIT_ * 130;
  float m_g = -1e30f;
#pragma unroll
  for (int sp = 0; sp < SPLIT_; ++sp) m_g = fmaxf(m_g, pbase[sp * 130 + 128]);
  float scale[SPLIT_];
  float l_g = 0.f;
#pragma unroll
  for (int sp = 0; sp < SPLIT_; ++sp) {
    scale[sp] = expf(pbase[sp * 130 + 128] - m_g);
    l_g += scale[sp] * pbase[sp * 130 + 129];
  }
  const float inv = 1.f / l_g;
  float c0 = 0.f, c1 = 0.f;
#pragma unroll
  for (int sp = 0; sp < SPLIT_; ++sp) {
    c0 += scale[sp] * pbase[sp * 130 + 2 * l];
    c1 += scale[sp] * pbase[sp * 130 + 2 * l + 1];
  }
  ctx[(size_t)bh * HD_ + 2 * l] = c0 * inv;
  ctx[(size_t)bh * HD_ + 2 * l + 1] = c1 * inv;
}

extern "C" void kernel_launch(void* const* d_in, const int* in_sizes, int n_in,
                              void* d_out, int out_size, void* d_ws, size_t ws_size,
                              hipStream_t stream) {
  const int* positions = (const int*)d_in[0];
  const float* hidden = (const float*)d_in[1];
  const float* k_cache = (const float*)d_in[2];
  const float* v_cache = (const float*)d_in[3];
  const float* w_qkv = (const float*)d_in[4];
  const float* w_o = (const float*)d_in[5];
  float* out = (float*)d_out;

  float* ws = (float*)d_ws;
  float* partA = ws;                                   // max(16*64*6144, 16*64*4096) = 6291456 floats
  float* qkv = partA + (size_t)KS * 64 * QKV_COLS;     // 393216
  float* qr = qkv + (size_t)64 * QKV_COLS;             // 262144
  float* kn = qr + (size_t)64 * NH_ * HD_;             // 65536
  float* vn = kn + (size_t)64 * NKV_ * HD_;            // 65536
  float* apart = vn + (size_t)64 * NKV_ * HD_;         // 64*32*4*130 = 1064960
  float* ctx = apart + (size_t)64 * NH_ * SPLIT_ * 130;// 262144
  // total ~8.4M floats (~33.6 MB) of d_ws

  gemm_part_k<<<dim3(QKV_COLS / 256, KS), 256, 0, stream>>>(hidden, w_qkv, partA, QKV_COLS);
  reduce16_k<<<(64 * QKV_COLS) / 256, 256, 0, stream>>>(partA, qkv, 64 * QKV_COLS);
  rope_k<<<dim3(B_SZ, NH_ + NKV_), 64, 0, stream>>>(qkv, positions, qr, kn, vn);
  attn_k<<<dim3(B_SZ, NKV_, SPLIT_), 256, 0, stream>>>(k_cache, v_cache, qr, kn, vn, apart);
  merge_k<<<B_SZ * NH_, 64, 0, stream>>>(apart, ctx);
  gemm_part_k<<<dim3(HID_ / 256, KS), 256, 0, stream>>>(ctx, w_o, partA, HID_);
  reduce16_k<<<(64 * HID_) / 256, 256, 0, stream>>>(partA, out, 64 * HID_);
}

// Round 2
// 666.061 us; speedup vs baseline: 1.4038x; 1.4038x over previous
//
#include <hip/hip_runtime.h>
#include <cstddef>

#define B_SZ 64
#define HID_ 4096
#define NH_ 32
#define NKV_ 8
#define HD_ 128
#define T_ 4096
#define QKV_COLS 6144                  // (NH + 2*NKV) * HD
#define SCALE_ 0.08838834764831845f    // 128^-0.5

#define KS 16                          // split-K for both GEMMs
#define G_IPER 256                     // HID_/KS
#define G_ROWS 4

#define SPLIT_ 4
#define KPB 1024                       // keys per block (T_/SPLIT_)

// ---------------------------------------------------------------- GEMM
// part[ks][64][ncol] = X[64][4096] @ W[4096][ncol], K-split by blockIdx.z.
// No LDS: W coalesced float4 x2 per thread, X via (uniform-address) scalar
// loads, depth-1 register prefetch on both.
#define FMA4(A, S, V) { A.x = fmaf(S, V.x, A.x); A.y = fmaf(S, V.y, A.y); \
                        A.z = fmaf(S, V.z, A.z); A.w = fmaf(S, V.w, A.w); }

__global__ __launch_bounds__(256) void gemm_k(const float* __restrict__ X,
                                              const float* __restrict__ W,
                                              float* __restrict__ part, int ncol) {
  const int tid = threadIdx.x;
  const int cA = blockIdx.x * 2048 + tid * 4;
  const int cB = cA + 1024;
  const int r0 = blockIdx.y * G_ROWS;
  const int i0 = blockIdx.z * G_IPER;

  float4 a00 = {0,0,0,0}, a01 = {0,0,0,0}, a10 = {0,0,0,0}, a11 = {0,0,0,0};
  float4 a20 = {0,0,0,0}, a21 = {0,0,0,0}, a30 = {0,0,0,0}, a31 = {0,0,0,0};

  const float* wpA = W + (size_t)i0 * ncol + cA;
  const float* wpB = W + (size_t)i0 * ncol + cB;
  const float* xp  = X + (size_t)r0 * HID_ + i0;   // uniform across block

  float4 wA = *(const float4*)wpA;
  float4 wB = *(const float4*)wpB;
  float x0 = xp[0], x1 = xp[HID_], x2 = xp[2 * HID_], x3 = xp[3 * HID_];

#define GEMM_BODY() \
  FMA4(a00, x0, wA) FMA4(a01, x0, wB) FMA4(a10, x1, wA) FMA4(a11, x1, wB) \
  FMA4(a20, x2, wA) FMA4(a21, x2, wB) FMA4(a30, x3, wA) FMA4(a31, x3, wB)

  for (int ii = 0; ii < G_IPER - 1; ++ii) {
    wpA += ncol; wpB += ncol;
    float4 nA = *(const float4*)wpA;
    float4 nB = *(const float4*)wpB;
    float n0 = xp[ii + 1];
    float n1 = xp[HID_ + ii + 1];
    float n2 = xp[2 * HID_ + ii + 1];
    float n3 = xp[3 * HID_ + ii + 1];
    GEMM_BODY();
    wA = nA; wB = nB; x0 = n0; x1 = n1; x2 = n2; x3 = n3;
  }
  GEMM_BODY();

  float* pp = part + ((size_t)blockIdx.z * 64 + r0) * ncol;
  *(float4*)(pp + cA) = a00;               *(float4*)(pp + cB) = a01;
  *(float4*)(pp + (size_t)ncol + cA) = a10; *(float4*)(pp + (size_t)ncol + cB) = a11;
  *(float4*)(pp + (size_t)2 * ncol + cA) = a20; *(float4*)(pp + (size_t)2 * ncol + cB) = a21;
  *(float4*)(pp + (size_t)3 * ncol + cA) = a30; *(float4*)(pp + (size_t)3 * ncol + cB) = a31;
}

__global__ __launch_bounds__(256) void reduce16_k(const float* __restrict__ part,
                                                  float* __restrict__ out, int n) {
  const int i4 = (blockIdx.x * 256 + threadIdx.x) * 4;
  if (i4 >= n) return;
  float4 s = *(const float4*)(part + i4);
#pragma unroll
  for (int k = 1; k < KS; ++k) {
    float4 t = *(const float4*)(part + (size_t)k * n + i4);
    s.x += t.x; s.y += t.y; s.z += t.z; s.w += t.w;
  }
  *(float4*)(out + i4) = s;
}

// ---------------------------------------------------------------- RoPE
__global__ __launch_bounds__(64) void rope_k(const float* __restrict__ qkv,
                                             const int* __restrict__ pos,
                                             float* __restrict__ qr,
                                             float* __restrict__ kn,
                                             float* __restrict__ vn) {
  const int b = blockIdx.x;
  const int hh = blockIdx.y;      // 0..31 q heads, 32..39 k heads
  const int d = threadIdx.x;      // 0..63
  const float p = (float)pos[b];
  const float invf = (float)pow(10000.0, -(double)d / 64.0);
  float sn, cs;
  sincosf(p * invf, &sn, &cs);
  const float* src;
  float* dst;
  if (hh < 32) {
    src = qkv + (size_t)b * QKV_COLS + hh * HD_;
    dst = qr + ((size_t)b * NH_ + hh) * HD_;
  } else {
    const int g = hh - 32;
    src = qkv + (size_t)b * QKV_COLS + NH_ * HD_ + g * HD_;
    dst = kn + ((size_t)b * NKV_ + g) * HD_;
    const float* vsrc = qkv + (size_t)b * QKV_COLS + (NH_ + NKV_) * HD_ + g * HD_;
    float* vdst = vn + ((size_t)b * NKV_ + g) * HD_;
    vdst[d] = vsrc[d];
    vdst[d + 64] = vsrc[d + 64];
  }
  const float x1 = src[d], x2 = src[d + 64];
  dst[d] = x1 * cs - x2 * sn;
  dst[d + 64] = x2 * cs + x1 * sn;
}

// ---------------------------------------------------------------- attention
// Block = (b, kv-head g, split). 8 lanes/key, 16 cols/lane (4 strided float4).
// Q + partial dots in registers; LDS only for scores/probs + final reduce.
__device__ __forceinline__ void load_row4(const float* p, float4 r[4]) {
  r[0] = *(const float4*)(p);
  r[1] = *(const float4*)(p + 32);
  r[2] = *(const float4*)(p + 64);
  r[3] = *(const float4*)(p + 96);
}

__global__ __launch_bounds__(256) void attn2_k(const float* __restrict__ kc,
                                               const float* __restrict__ vc,
                                               const float* __restrict__ qr,
                                               const float* __restrict__ kn,
                                               const float* __restrict__ vn,
                                               float* __restrict__ part) {
  __shared__ float lds_buf[8448];                  // union: scores[4][1028] | red[2][32][132]
  float (*s_all)[1028] = (float (*)[1028])lds_buf;

  const int b = blockIdx.x, g = blockIdx.y, sp = blockIdx.z;
  const int tid = threadIdx.x;
  const int w = tid >> 6, l = tid & 63;
  const int cg = tid & 7, ko = tid >> 3;           // ko in 0..31 (key owner)
  const bool has_new = (sp == SPLIT_ - 1);

  // Q fragments: q4[h][i] covers cols i*32 + cg*4 .. +3 of head g*4+h
  float4 q4[4][4];
  const float* qb = qr + (size_t)(b * NH_ + g * 4) * HD_ + cg * 4;
#pragma unroll
  for (int h = 0; h < 4; ++h)
#pragma unroll
    for (int i = 0; i < 4; ++i) {
      float4 t = *(const float4*)(qb + h * HD_ + i * 32);
      q4[h][i] = make_float4(t.x * SCALE_, t.y * SCALE_, t.z * SCALE_, t.w * SCALE_);
    }

  const size_t row_stride = (size_t)NKV_ * HD_;
  const float* kb = kc + ((size_t)(b * T_ + sp * KPB) * NKV_ + g) * HD_ + cg * 4;
  const float* vb = vc + ((size_t)(b * T_ + sp * KPB) * NKV_ + g) * HD_ + cg * 4;

  // ---- phase 1: scores (32 iters x 32 keys), no LDS staging
  {
    float4 kx[4];
    load_row4(kb + (size_t)ko * row_stride, kx);
    for (int it = 0; it < 32; ++it) {
      float4 nx[4];
      const int itn = (it + 1) & 31;               // wraps to valid rows
      load_row4(kb + (size_t)(itn * 32 + ko) * row_stride, nx);
      float s[4] = {0.f, 0.f, 0.f, 0.f};
#pragma unroll
      for (int i = 0; i < 4; ++i) {
#pragma unroll
        for (int h = 0; h < 4; ++h) {
          s[h] = fmaf(q4[h][i].x, kx[i].x, s[h]);
          s[h] = fmaf(q4[h][i].y, kx[i].y, s[h]);
          s[h] = fmaf(q4[h][i].z, kx[i].z, s[h]);
          s[h] = fmaf(q4[h][i].w, kx[i].w, s[h]);
        }
      }
#pragma unroll
      for (int h = 0; h < 4; ++h) {
        s[h] += __shfl_xor(s[h], 1);
        s[h] += __shfl_xor(s[h], 2);
        s[h] += __shfl_xor(s[h], 4);
      }
      if (cg == 0) {
        const int key = it * 32 + ko;
#pragma unroll
        for (int h = 0; h < 4; ++h) s_all[h][key] = s[h];
      }
#pragma unroll
      for (int i = 0; i < 4; ++i) kx[i] = nx[i];
    }
  }

  // ---- new-token score (head w computed by lanes l<8 of wave w)
  if (has_new && l < 8) {
    const float* kp = kn + (size_t)(b * NKV_ + g) * HD_ + cg * 4;
    float4 kx2[4];
    load_row4(kp, kx2);
    float sn = 0.f;
#pragma unroll
    for (int i = 0; i < 4; ++i) {
      sn = fmaf(q4[w][i].x, kx2[i].x, sn);
      sn = fmaf(q4[w][i].y, kx2[i].y, sn);
      sn = fmaf(q4[w][i].z, kx2[i].z, sn);
      sn = fmaf(q4[w][i].w, kx2[i].w, sn);
    }
    sn += __shfl_xor(sn, 1);
    sn += __shfl_xor(sn, 2);
    sn += __shfl_xor(sn, 4);
    if (l == 0) s_all[w][1024] = sn;
  }
  __syncthreads();

  // ---- per-head softmax over this split (wave w owns head w)
  {
    float vals[16];
    float mloc = -1e30f;
#pragma unroll
    for (int k = 0; k < 16; ++k) {
      vals[k] = s_all[w][k * 64 + l];
      mloc = fmaxf(mloc, vals[k]);
    }
#pragma unroll
    for (int m = 32; m > 0; m >>= 1) mloc = fmaxf(mloc, __shfl_xor(mloc, m));
    float s_extra = 0.f;
    if (has_new) {
      s_extra = s_all[w][1024];
      mloc = fmaxf(mloc, s_extra);
    }
    float lsum = 0.f;
#pragma unroll
    for (int k = 0; k < 16; ++k) {
      float e = expf(vals[k] - mloc);
      lsum += e;
      s_all[w][k * 64 + l] = e;
    }
#pragma unroll
    for (int m = 32; m > 0; m >>= 1) lsum += __shfl_xor(lsum, m);
    if (has_new) {
      float en = expf(s_extra - mloc);
      lsum += en;
      if (l == 0) s_all[w][1024] = en;
    }
    if (l == 0) {
      float* pp = part + ((size_t)(b * NH_ + g * 4 + w) * SPLIT_ + sp) * 130;
      pp[128] = mloc;
      pp[129] = lsum;
    }
  }
  __syncthreads();

  // ---- phase 2: PV, register accumulators acc[h][i]
  float4 acc[4][4];
#pragma unroll
  for (int h = 0; h < 4; ++h)
#pragma unroll
    for (int i = 0; i < 4; ++i) acc[h][i] = make_float4(0.f, 0.f, 0.f, 0.f);

  {
    float4 vx[4];
    load_row4(vb + (size_t)ko * row_stride, vx);
    for (int it = 0; it < 32; ++it) {
      float4 nx[4];
      const int itn = (it + 1) & 31;
      load_row4(vb + (size_t)(itn * 32 + ko) * row_stride, nx);
      const int key = it * 32 + ko;
      float p[4];
#pragma unroll
      for (int h = 0; h < 4; ++h) p[h] = s_all[h][key];
#pragma unroll
      for (int h = 0; h < 4; ++h)
#pragma unroll
        for (int i = 0; i < 4; ++i) FMA4(acc[h][i], p[h], vx[i]);
#pragma unroll
      for (int i = 0; i < 4; ++i) vx[i] = nx[i];
    }
  }

  if (has_new && ko == 0) {   // lanes 0..7 cover all 128 cols once
    float en[4];
#pragma unroll
    for (int h = 0; h < 4; ++h) en[h] = s_all[h][1024];
    const float* vp = vn + (size_t)(b * NKV_ + g) * HD_ + cg * 4;
    float4 vx2[4];
    load_row4(vp, vx2);
#pragma unroll
    for (int h = 0; h < 4; ++h)
#pragma unroll
      for (int i = 0; i < 4; ++i) FMA4(acc[h][i], en[h], vx2[i]);
  }

  // ---- block reduce over the 32 key-owners, 2 heads per round
  float4* red4 = (float4*)lds_buf;     // [2][32][33] float4 (132 floats/row)
#pragma unroll
  for (int r = 0; r < 2; ++r) {
    __syncthreads();                   // r0: probs reads done; r1: prev reads done
#pragma unroll
    for (int hh = 0; hh < 2; ++hh) {
      const int h = r * 2 + hh;
#pragma unroll
      for (int i = 0; i < 4; ++i)
        red4[(size_t)(hh * 32 + ko) * 33 + i * 8 + cg] = acc[h][i];
    }
    __syncthreads();
    const int hh2 = tid >> 7;          // 0..1
    const int col = tid & 127;
    const float* redf = lds_buf + (size_t)(hh2 * 32) * 132 + col;
    float ssum = 0.f;
#pragma unroll
    for (int k2 = 0; k2 < 32; ++k2) ssum += redf[(size_t)k2 * 132];
    const int h = r * 2 + hh2;
    part[((size_t)(b * NH_ + g * 4 + h) * SPLIT_ + sp) * 130 + col] = ssum;
  }
}

// ---------------------------------------------------------------- merge splits
__global__ __launch_bounds__(64) void merge_k(const float* __restrict__ part,
                                              float* __restrict__ ctx) {
  const int bh = blockIdx.x;
  const int l = threadIdx.x;
  const float* pbase = part + (size_t)bh * SPLIT_ * 130;
  float m_g = -1e30f;
#pragma unroll
  for (int sp = 0; sp < SPLIT_; ++sp) m_g = fmaxf(m_g, pbase[sp * 130 + 128]);
  float scale[SPLIT_];
  float l_g = 0.f;
#pragma unroll
  for (int sp = 0; sp < SPLIT_; ++sp) {
    scale[sp] = expf(pbase[sp * 130 + 128] - m_g);
    l_g += scale[sp] * pbase[sp * 130 + 129];
  }
  const float inv = 1.f / l_g;
  float c0 = 0.f, c1 = 0.f;
#pragma unroll
  for (int sp = 0; sp < SPLIT_; ++sp) {
    c0 += scale[sp] * pbase[sp * 130 + 2 * l];
    c1 += scale[sp] * pbase[sp * 130 + 2 * l + 1];
  }
  ctx[(size_t)bh * HD_ + 2 * l] = c0 * inv;
  ctx[(size_t)bh * HD_ + 2 * l + 1] = c1 * inv;
}

extern "C" void kernel_launch(void* const* d_in, const int* in_sizes, int n_in,
                              void* d_out, int out_size, void* d_ws, size_t ws_size,
                              hipStream_t stream) {
  const int* positions = (const int*)d_in[0];
  const float* hidden = (const float*)d_in[1];
  const float* k_cache = (const float*)d_in[2];
  const float* v_cache = (const float*)d_in[3];
  const float* w_qkv = (const float*)d_in[4];
  const float* w_o = (const float*)d_in[5];
  float* out = (float*)d_out;

  float* ws = (float*)d_ws;
  float* partA = ws;                                    // 16*64*6144 = 6291456
  float* qkv = partA + (size_t)KS * 64 * QKV_COLS;      // 393216
  float* qr = qkv + (size_t)64 * QKV_COLS;              // 262144
  float* kn = qr + (size_t)64 * NH_ * HD_;              // 65536
  float* vn = kn + (size_t)64 * NKV_ * HD_;             // 65536
  float* apart = vn + (size_t)64 * NKV_ * HD_;          // 64*32*4*130 = 1064960
  float* ctx = apart + (size_t)64 * NH_ * SPLIT_ * 130; // 262144

  gemm_k<<<dim3(3, 16, KS), 256, 0, stream>>>(hidden, w_qkv, partA, QKV_COLS);
  reduce16_k<<<(64 * QKV_COLS) / 1024, 256, 0, stream>>>(partA, qkv, 64 * QKV_COLS);
  rope_k<<<dim3(B_SZ, NH_ + NKV_), 64, 0, stream>>>(qkv, positions, qr, kn, vn);
  attn2_k<<<dim3(B_SZ, NKV_, SPLIT_), 256, 0, stream>>>(k_cache, v_cache, qr, kn, vn, apart);
  merge_k<<<B_SZ * NH_, 64, 0, stream>>>(apart, ctx);
  gemm_k<<<dim3(2, 16, KS), 256, 0, stream>>>(ctx, w_o, partA, HID_);
  reduce16_k<<<(64 * HID_) / 1024, 256, 0, stream>>>(partA, out, 64 * HID_);
}

// Round 3
// 606.409 us; speedup vs baseline: 1.5419x; 1.0984x over previous
//
#include <hip/hip_runtime.h>
#include <cstddef>

#define B_SZ 64
#define HID_ 4096
#define NH_ 32
#define NKV_ 8
#define HD_ 128
#define T_ 4096
#define QKV_COLS 6144                  // (NH + 2*NKV) * HD
#define SCALE_ 0.08838834764831845f    // 128^-0.5

#define KS 16                          // split-K for both GEMMs
#define G_KCH (HID_ / KS)              // 256 k-steps per block
#define G_RPB 32                       // rows of X per block (2 y-blocks cover 64)

#define SPLIT_ 4
#define KPB 1024                       // keys per block (T_/SPLIT_)

#define FMA4(A, S, V) { A.x = fmaf(S, V.x, A.x); A.y = fmaf(S, V.y, A.y); \
                        A.z = fmaf(S, V.z, A.z); A.w = fmaf(S, V.w, A.w); }

// ---------------------------------------------------------------- X transpose
// X[64][4096] -> XT[4096][64] (1 MB; makes X reads scalar-loadable in gemm_k)
__global__ __launch_bounds__(256) void transpose_k(const float* __restrict__ X,
                                                   float* __restrict__ XT) {
  const int idx = blockIdx.x * 256 + threadIdx.x;
  const int k = idx >> 6, r = idx & 63;
  XT[idx] = X[(size_t)r * HID_ + k];
}

// ---------------------------------------------------------------- GEMM
// part[z][64][ncol] = X[64][4096] @ W[4096][ncol], k-split by blockIdx.z.
// Thread owns 1 column x 32 rows: one W load feeds 32 FMAs; X is block-uniform
// -> contiguous scalar loads from XT (no LDS, no VGPR cost). W prefetch depth 4.
__global__ __launch_bounds__(256) void gemm_k(const float* __restrict__ XT,
                                              const float* __restrict__ W,
                                              float* __restrict__ part, int ncol) {
  const int tid = threadIdx.x;
  const int col = blockIdx.x * 256 + tid;
  const int r0 = blockIdx.y * G_RPB;
  const int k0 = blockIdx.z * G_KCH;

  float acc[G_RPB];
#pragma unroll
  for (int r = 0; r < G_RPB; ++r) acc[r] = 0.f;

  const float* wp = W + (size_t)k0 * ncol + col;
  const float* xp = XT + (size_t)k0 * 64 + r0;

  float w0 = wp[0];
  float w1 = wp[(size_t)1 * ncol];
  float w2 = wp[(size_t)2 * ncol];
  float w3 = wp[(size_t)3 * ncol];

  for (int k = 0; k < G_KCH; k += 4) {
    float n0 = 0.f, n1 = 0.f, n2 = 0.f, n3 = 0.f;
    if (k + 4 < G_KCH) {
      const float* wq = wp + (size_t)(k + 4) * ncol;
      n0 = wq[0];
      n1 = wq[(size_t)1 * ncol];
      n2 = wq[(size_t)2 * ncol];
      n3 = wq[(size_t)3 * ncol];
    }
#pragma unroll
    for (int u = 0; u < 4; ++u) {
      const float wv = (u == 0) ? w0 : (u == 1) ? w1 : (u == 2) ? w2 : w3;
      const float* xk = xp + (size_t)(k + u) * 64;   // block-uniform -> s_load
#pragma unroll
      for (int r = 0; r < G_RPB; ++r) acc[r] = fmaf(xk[r], wv, acc[r]);
    }
    w0 = n0; w1 = n1; w2 = n2; w3 = n3;
  }

  float* pp = part + ((size_t)blockIdx.z * 64 + r0) * ncol + col;
#pragma unroll
  for (int r = 0; r < G_RPB; ++r) pp[(size_t)r * ncol] = acc[r];
}

__global__ __launch_bounds__(256) void reduce16_k(const float* __restrict__ part,
                                                  float* __restrict__ out, int n) {
  const int i4 = (blockIdx.x * 256 + threadIdx.x) * 4;
  if (i4 >= n) return;
  float4 s = *(const float4*)(part + i4);
#pragma unroll
  for (int k = 1; k < KS; ++k) {
    float4 t = *(const float4*)(part + (size_t)k * n + i4);
    s.x += t.x; s.y += t.y; s.z += t.z; s.w += t.w;
  }
  *(float4*)(out + i4) = s;
}

// ---------------------------------------------------------------- RoPE
__global__ __launch_bounds__(64) void rope_k(const float* __restrict__ qkv,
                                             const int* __restrict__ pos,
                                             float* __restrict__ qr,
                                             float* __restrict__ kn,
                                             float* __restrict__ vn) {
  const int b = blockIdx.x;
  const int hh = blockIdx.y;      // 0..31 q heads, 32..39 k heads
  const int d = threadIdx.x;      // 0..63
  const float p = (float)pos[b];
  const float invf = (float)pow(10000.0, -(double)d / 64.0);
  float sn, cs;
  sincosf(p * invf, &sn, &cs);
  const float* src;
  float* dst;
  if (hh < 32) {
    src = qkv + (size_t)b * QKV_COLS + hh * HD_;
    dst = qr + ((size_t)b * NH_ + hh) * HD_;
  } else {
    const int g = hh - 32;
    src = qkv + (size_t)b * QKV_COLS + NH_ * HD_ + g * HD_;
    dst = kn + ((size_t)b * NKV_ + g) * HD_;
    const float* vsrc = qkv + (size_t)b * QKV_COLS + (NH_ + NKV_) * HD_ + g * HD_;
    float* vdst = vn + ((size_t)b * NKV_ + g) * HD_;
    vdst[d] = vsrc[d];
    vdst[d + 64] = vsrc[d + 64];
  }
  const float x1 = src[d], x2 = src[d + 64];
  dst[d] = x1 * cs - x2 * sn;
  dst[d + 64] = x2 * cs + x1 * sn;
}

// ---------------------------------------------------------------- attention
__device__ __forceinline__ void load_row4(const float* p, float4 r[4]) {
  r[0] = *(const float4*)(p);
  r[1] = *(const float4*)(p + 32);
  r[2] = *(const float4*)(p + 64);
  r[3] = *(const float4*)(p + 96);
}

__global__ __launch_bounds__(256) void attn2_k(const float* __restrict__ kc,
                                               const float* __restrict__ vc,
                                               const float* __restrict__ qr,
                                               const float* __restrict__ kn,
                                               const float* __restrict__ vn,
                                               float* __restrict__ part) {
  __shared__ float lds_buf[8448];                  // union: scores[4][1028] | red[2][32][132]
  float (*s_all)[1028] = (float (*)[1028])lds_buf;

  const int b = blockIdx.x, g = blockIdx.y, sp = blockIdx.z;
  const int tid = threadIdx.x;
  const int w = tid >> 6, l = tid & 63;
  const int cg = tid & 7, ko = tid >> 3;           // ko in 0..31 (key owner)
  const bool has_new = (sp == SPLIT_ - 1);

  float4 q4[4][4];
  const float* qb = qr + (size_t)(b * NH_ + g * 4) * HD_ + cg * 4;
#pragma unroll
  for (int h = 0; h < 4; ++h)
#pragma unroll
    for (int i = 0; i < 4; ++i) {
      float4 t = *(const float4*)(qb + h * HD_ + i * 32);
      q4[h][i] = make_float4(t.x * SCALE_, t.y * SCALE_, t.z * SCALE_, t.w * SCALE_);
    }

  const size_t row_stride = (size_t)NKV_ * HD_;
  const float* kb = kc + ((size_t)(b * T_ + sp * KPB) * NKV_ + g) * HD_ + cg * 4;
  const float* vb = vc + ((size_t)(b * T_ + sp * KPB) * NKV_ + g) * HD_ + cg * 4;

  // ---- phase 1: scores
  {
    float4 kx[4];
    load_row4(kb + (size_t)ko * row_stride, kx);
    for (int it = 0; it < 32; ++it) {
      float4 nx[4];
      const int itn = (it + 1) & 31;
      load_row4(kb + (size_t)(itn * 32 + ko) * row_stride, nx);
      float s[4] = {0.f, 0.f, 0.f, 0.f};
#pragma unroll
      for (int i = 0; i < 4; ++i) {
#pragma unroll
        for (int h = 0; h < 4; ++h) {
          s[h] = fmaf(q4[h][i].x, kx[i].x, s[h]);
          s[h] = fmaf(q4[h][i].y, kx[i].y, s[h]);
          s[h] = fmaf(q4[h][i].z, kx[i].z, s[h]);
          s[h] = fmaf(q4[h][i].w, kx[i].w, s[h]);
        }
      }
#pragma unroll
      for (int h = 0; h < 4; ++h) {
        s[h] += __shfl_xor(s[h], 1);
        s[h] += __shfl_xor(s[h], 2);
        s[h] += __shfl_xor(s[h], 4);
      }
      if (cg == 0) {
        const int key = it * 32 + ko;
#pragma unroll
        for (int h = 0; h < 4; ++h) s_all[h][key] = s[h];
      }
#pragma unroll
      for (int i = 0; i < 4; ++i) kx[i] = nx[i];
    }
  }

  if (has_new && l < 8) {
    const float* kp = kn + (size_t)(b * NKV_ + g) * HD_ + cg * 4;
    float4 kx2[4];
    load_row4(kp, kx2);
    float sn = 0.f;
#pragma unroll
    for (int i = 0; i < 4; ++i) {
      sn = fmaf(q4[w][i].x, kx2[i].x, sn);
      sn = fmaf(q4[w][i].y, kx2[i].y, sn);
      sn = fmaf(q4[w][i].z, kx2[i].z, sn);
      sn = fmaf(q4[w][i].w, kx2[i].w, sn);
    }
    sn += __shfl_xor(sn, 1);
    sn += __shfl_xor(sn, 2);
    sn += __shfl_xor(sn, 4);
    if (l == 0) s_all[w][1024] = sn;
  }
  __syncthreads();

  // ---- softmax (wave w owns head w)
  {
    float vals[16];
    float mloc = -1e30f;
#pragma unroll
    for (int k = 0; k < 16; ++k) {
      vals[k] = s_all[w][k * 64 + l];
      mloc = fmaxf(mloc, vals[k]);
    }
#pragma unroll
    for (int m = 32; m > 0; m >>= 1) mloc = fmaxf(mloc, __shfl_xor(mloc, m));
    float s_extra = 0.f;
    if (has_new) {
      s_extra = s_all[w][1024];
      mloc = fmaxf(mloc, s_extra);
    }
    float lsum = 0.f;
#pragma unroll
    for (int k = 0; k < 16; ++k) {
      float e = expf(vals[k] - mloc);
      lsum += e;
      s_all[w][k * 64 + l] = e;
    }
#pragma unroll
    for (int m = 32; m > 0; m >>= 1) lsum += __shfl_xor(lsum, m);
    if (has_new) {
      float en = expf(s_extra - mloc);
      lsum += en;
      if (l == 0) s_all[w][1024] = en;
    }
    if (l == 0) {
      float* pp = part + ((size_t)(b * NH_ + g * 4 + w) * SPLIT_ + sp) * 130;
      pp[128] = mloc;
      pp[129] = lsum;
    }
  }
  __syncthreads();

  // ---- phase 2: PV
  float4 acc[4][4];
#pragma unroll
  for (int h = 0; h < 4; ++h)
#pragma unroll
    for (int i = 0; i < 4; ++i) acc[h][i] = make_float4(0.f, 0.f, 0.f, 0.f);

  {
    float4 vx[4];
    load_row4(vb + (size_t)ko * row_stride, vx);
    for (int it = 0; it < 32; ++it) {
      float4 nx[4];
      const int itn = (it + 1) & 31;
      load_row4(vb + (size_t)(itn * 32 + ko) * row_stride, nx);
      const int key = it * 32 + ko;
      float p[4];
#pragma unroll
      for (int h = 0; h < 4; ++h) p[h] = s_all[h][key];
#pragma unroll
      for (int h = 0; h < 4; ++h)
#pragma unroll
        for (int i = 0; i < 4; ++i) FMA4(acc[h][i], p[h], vx[i]);
#pragma unroll
      for (int i = 0; i < 4; ++i) vx[i] = nx[i];
    }
  }

  if (has_new && ko == 0) {
    float en[4];
#pragma unroll
    for (int h = 0; h < 4; ++h) en[h] = s_all[h][1024];
    const float* vp = vn + (size_t)(b * NKV_ + g) * HD_ + cg * 4;
    float4 vx2[4];
    load_row4(vp, vx2);
#pragma unroll
    for (int h = 0; h < 4; ++h)
#pragma unroll
      for (int i = 0; i < 4; ++i) FMA4(acc[h][i], en[h], vx2[i]);
  }

  // ---- block reduce over key-owners
  float4* red4 = (float4*)lds_buf;     // [2][32][33] float4
#pragma unroll
  for (int r = 0; r < 2; ++r) {
    __syncthreads();
#pragma unroll
    for (int hh = 0; hh < 2; ++hh) {
      const int h = r * 2 + hh;
#pragma unroll
      for (int i = 0; i < 4; ++i)
        red4[(size_t)(hh * 32 + ko) * 33 + i * 8 + cg] = acc[h][i];
    }
    __syncthreads();
    const int hh2 = tid >> 7;
    const int col = tid & 127;
    const float* redf = lds_buf + (size_t)(hh2 * 32) * 132 + col;
    float ssum = 0.f;
#pragma unroll
    for (int k2 = 0; k2 < 32; ++k2) ssum += redf[(size_t)k2 * 132];
    const int h = r * 2 + hh2;
    part[((size_t)(b * NH_ + g * 4 + h) * SPLIT_ + sp) * 130 + col] = ssum;
  }
}

// ---------------------------------------------------------------- merge splits
// writes ctx TRANSPOSED: ctxt[col(4096)][b(64)] so gemm2 can scalar-load it
__global__ __launch_bounds__(64) void merge_k(const float* __restrict__ part,
                                              float* __restrict__ ctxt) {
  const int bh = blockIdx.x;
  const int b = bh >> 5, h = bh & 31;
  const int l = threadIdx.x;
  const float* pbase = part + (size_t)bh * SPLIT_ * 130;
  float m_g = -1e30f;
#pragma unroll
  for (int sp = 0; sp < SPLIT_; ++sp) m_g = fmaxf(m_g, pbase[sp * 130 + 128]);
  float scale[SPLIT_];
  float l_g = 0.f;
#pragma unroll
  for (int sp = 0; sp < SPLIT_; ++sp) {
    scale[sp] = expf(pbase[sp * 130 + 128] - m_g);
    l_g += scale[sp] * pbase[sp * 130 + 129];
  }
  const float inv = 1.f / l_g;
  float c0 = 0.f, c1 = 0.f;
#pragma unroll
  for (int sp = 0; sp < SPLIT_; ++sp) {
    c0 += scale[sp] * pbase[sp * 130 + 2 * l];
    c1 += scale[sp] * pbase[sp * 130 + 2 * l + 1];
  }
  ctxt[((size_t)(h * HD_ + 2 * l)) * 64 + b] = c0 * inv;
  ctxt[((size_t)(h * HD_ + 2 * l + 1)) * 64 + b] = c1 * inv;
}

extern "C" void kernel_launch(void* const* d_in, const int* in_sizes, int n_in,
                              void* d_out, int out_size, void* d_ws, size_t ws_size,
                              hipStream_t stream) {
  const int* positions = (const int*)d_in[0];
  const float* hidden = (const float*)d_in[1];
  const float* k_cache = (const float*)d_in[2];
  const float* v_cache = (const float*)d_in[3];
  const float* w_qkv = (const float*)d_in[4];
  const float* w_o = (const float*)d_in[5];
  float* out = (float*)d_out;

  float* ws = (float*)d_ws;
  float* partA = ws;                                    // 16*64*6144 = 6291456
  float* qkv = partA + (size_t)KS * 64 * QKV_COLS;      // 393216
  float* qr = qkv + (size_t)64 * QKV_COLS;              // 262144
  float* kn = qr + (size_t)64 * NH_ * HD_;              // 65536
  float* vn = kn + (size_t)64 * NKV_ * HD_;             // 65536
  float* apart = vn + (size_t)64 * NKV_ * HD_;          // 64*32*4*130 = 1064960
  float* xt = apart + (size_t)64 * NH_ * SPLIT_ * 130;  // 262144
  float* ctxt = xt + (size_t)64 * HID_;                 // 262144

  transpose_k<<<1024, 256, 0, stream>>>(hidden, xt);
  gemm_k<<<dim3(QKV_COLS / 256, 2, KS), 256, 0, stream>>>(xt, w_qkv, partA, QKV_COLS);
  reduce16_k<<<(64 * QKV_COLS) / 1024, 256, 0, stream>>>(partA, qkv, 64 * QKV_COLS);
  rope_k<<<dim3(B_SZ, NH_ + NKV_), 64, 0, stream>>>(qkv, positions, qr, kn, vn);
  attn2_k<<<dim3(B_SZ, NKV_, SPLIT_), 256, 0, stream>>>(k_cache, v_cache, qr, kn, vn, apart);
  merge_k<<<B_SZ * NH_, 64, 0, stream>>>(apart, ctxt);
  gemm_k<<<dim3(HID_ / 256, 2, KS), 256, 0, stream>>>(ctxt, w_o, partA, HID_);
  reduce16_k<<<(64 * HID_) / 1024, 256, 0, stream>>>(partA, out, 64 * HID_);
}